// Round 3
// baseline (260.020 us; speedup 1.0000x reference)
//
#include <hip/hip_runtime.h>
#include <hip/hip_bf16.h>

#define NN      50000
#define INDIM   512
#define HIDDEN  256
#define NE      800000
#define BIASF   0.0001f

typedef __attribute__((ext_vector_type(4))) float  f32x4;
typedef __attribute__((ext_vector_type(4))) __bf16 bf16x4;
typedef __attribute__((ext_vector_type(8))) __bf16 bf16x8;

// ---------------------------------------------------------------------------
// prep: blocks 0..31   : Wtb[n][k] = (bf16)W_emb[k][n] via coalesced LDS transpose
//       blocks 32..227 : g[idx] = 0
//       block  228     : w_sym[j] = 0.5*(We[j]+We[j+256])
// ---------------------------------------------------------------------------
__global__ __launch_bounds__(256) void prep_kernel(const float* __restrict__ W_emb,
                                                   const float* __restrict__ W_edge,
                                                   __bf16* __restrict__ Wtb,
                                                   float* __restrict__ w_sym,
                                                   float* __restrict__ g) {
    const int b   = blockIdx.x;
    const int tid = threadIdx.x;
    if (b < 32) {
        // 64(k) x 64(n) f32 tile transpose; 8 k-tiles x 4 n-tiles
        __shared__ float t[64 * 65];
        const int kt = (b >> 2) * 64;
        const int nt = (b & 3) * 64;
        const int rr = tid >> 4;           // 0..15
        const int cc = (tid & 15) * 4;     // 0..60
#pragma unroll
        for (int p = 0; p < 4; ++p) {
            int r = p * 16 + rr;           // k within tile
            f32x4 v = *(const f32x4*)&W_emb[(size_t)(kt + r) * HIDDEN + nt + cc];
            t[(cc + 0) * 65 + r] = v[0];   // store transposed: t[n][k]
            t[(cc + 1) * 65 + r] = v[1];
            t[(cc + 2) * 65 + r] = v[2];
            t[(cc + 3) * 65 + r] = v[3];
        }
        __syncthreads();
#pragma unroll
        for (int p = 0; p < 4; ++p) {
            int n = p * 16 + rr;           // n within tile
            bf16x4 o;
            o[0] = (__bf16)t[n * 65 + cc + 0];
            o[1] = (__bf16)t[n * 65 + cc + 1];
            o[2] = (__bf16)t[n * 65 + cc + 2];
            o[3] = (__bf16)t[n * 65 + cc + 3];
            *(bf16x4*)&Wtb[(size_t)(nt + n) * INDIM + kt + cc] = o;
        }
    } else if (b < 228) {
        int idx = (b - 32) * 256 + tid;    // 196*256 = 50176 >= NN
        if (idx < NN) g[idx] = 0.0f;
    } else {
        w_sym[tid] = 0.5f * (W_edge[tid] + W_edge[tid + HIDDEN]);
    }
}

// ---------------------------------------------------------------------------
// Barrier-free register GEMM + fused node-dot:
//   g[m] += sum_n relu(emb[m]@W[:,n] + b[n]) * w_sym[n]
// No LDS. A fragments: fp32 direct from embedding + packed cvt (L2/L3-fed).
// B fragments: bf16x8 direct from Wtb[n][k] (256 KB, L1/L2-resident).
// All 16 k-step offsets are compile-time immediates -> zero address VALU,
// no barriers -> compiler hoists loads freely across the unrolled loop.
// Block 256 thr = 2x2 waves; wave owns 32 rows x 64 cols (acc 2x4 f32x4).
// ---------------------------------------------------------------------------
__global__ __launch_bounds__(256, 5) void gemm_g_kernel(const float* __restrict__ A,
                                                        const __bf16* __restrict__ Wtb,
                                                        const float* __restrict__ bias,
                                                        const float* __restrict__ w_sym,
                                                        float* __restrict__ g) {
    const int tid  = threadIdx.x;
    const int lane = tid & 63;
    const int w    = tid >> 6;
    const int wm   = w >> 1, wn = w & 1;
    const int ml   = lane & 15, kq = lane >> 4;
    const int m0   = blockIdx.y * 64;
    const int n0   = blockIdx.x * 128;

    // fragment base pointers (lane-fixed); k advances via immediate offsets
    const float* ap[2];
#pragma unroll
    for (int mt = 0; mt < 2; ++mt) {
        int row = m0 + wm * 32 + mt * 16 + ml;
        if (row > NN - 1) row = NN - 1;                 // M-tail clamp (guarded at store)
        ap[mt] = A + (size_t)row * INDIM + kq * 8;
    }
    const __bf16* bp[4];
#pragma unroll
    for (int nt = 0; nt < 4; ++nt) {
        int col = n0 + wn * 64 + nt * 16 + ml;
        bp[nt] = Wtb + (size_t)col * INDIM + kq * 8;
    }

    f32x4 acc[2][4];
#pragma unroll
    for (int mt = 0; mt < 2; ++mt)
#pragma unroll
        for (int nt = 0; nt < 4; ++nt) acc[mt][nt] = (f32x4)0.0f;

#pragma unroll
    for (int ks = 0; ks < 16; ++ks) {
        bf16x8 af[2], bf[4];
#pragma unroll
        for (int mt = 0; mt < 2; ++mt) {
            f32x4 lo = *(const f32x4*)(ap[mt] + ks * 32);
            f32x4 hi = *(const f32x4*)(ap[mt] + ks * 32 + 4);
            af[mt][0] = (__bf16)lo[0]; af[mt][1] = (__bf16)lo[1];
            af[mt][2] = (__bf16)lo[2]; af[mt][3] = (__bf16)lo[3];
            af[mt][4] = (__bf16)hi[0]; af[mt][5] = (__bf16)hi[1];
            af[mt][6] = (__bf16)hi[2]; af[mt][7] = (__bf16)hi[3];
        }
#pragma unroll
        for (int nt = 0; nt < 4; ++nt)
            bf[nt] = *(const bf16x8*)(bp[nt] + ks * 32);
#pragma unroll
        for (int mt = 0; mt < 2; ++mt)
#pragma unroll
            for (int nt = 0; nt < 4; ++nt)
                acc[mt][nt] = __builtin_amdgcn_mfma_f32_16x16x32_bf16(
                    af[mt], bf[nt], acc[mt][nt], 0, 0, 0);
    }

    // epilogue: per-row dot with w_sym over this wave's 64 cols,
    // xor-shuffle reduce across the 16 ml-lanes, atomicAdd into g.
    // C/D layout: col = ml, row = kq*4 + reg  [verified m89/m91]
    float wsv[4], bcv[4];
#pragma unroll
    for (int nt = 0; nt < 4; ++nt) {
        int col = n0 + wn * 64 + nt * 16 + ml;
        wsv[nt] = w_sym[col];
        bcv[nt] = bias[col];
    }
#pragma unroll
    for (int mt = 0; mt < 2; ++mt) {
#pragma unroll
        for (int r = 0; r < 4; ++r) {
            float s = 0.0f;
#pragma unroll
            for (int nt = 0; nt < 4; ++nt) {
                float x = acc[mt][nt][r] + bcv[nt];
                s = fmaf(fmaxf(x, 0.0f), wsv[nt], s);
            }
            s += __shfl_xor(s, 1);
            s += __shfl_xor(s, 2);
            s += __shfl_xor(s, 4);
            s += __shfl_xor(s, 8);
            int row = m0 + wm * 32 + mt * 16 + kq * 4 + r;
            if (ml == 0 && row < NN) atomicAdd(&g[row], s);
        }
    }
}

// ---------------------------------------------------------------------------
// edge kernel: one THREAD per edge; g gathers are 4B hits in a 200 KB array.
// ---------------------------------------------------------------------------
__global__ __launch_bounds__(256) void edge_kernel(const float* __restrict__ g,
                                                   const int* __restrict__ edges,
                                                   const float* __restrict__ u,
                                                   const float* __restrict__ b_edge,
                                                   float* __restrict__ out) {
    const int e  = blockIdx.x * 256 + threadIdx.x;      // NE = 3125*256 exactly
    const int i0 = edges[e];
    const int i1 = edges[NE + e];
    float raw = g[i0] + g[i1] + b_edge[0];
    float uu  = u[e];
    float eps = fmaf(uu, BIASF - (1.0f - BIASF), 1.0f - BIASF); // -0.9998u+0.9999
    float gt  = logf(eps) - log1pf(-eps) + raw;                 // TEMPERATURE=1
    out[e] = 1.0f / (1.0f + expf(-gt));
}

// ---------------------------------------------------------------------------
extern "C" void kernel_launch(void* const* d_in, const int* in_sizes, int n_in,
                              void* d_out, int out_size, void* d_ws, size_t ws_size,
                              hipStream_t stream) {
    const float* embedding = (const float*)d_in[0];
    const float* u         = (const float*)d_in[2];
    const int*   edges     = (const int*)d_in[1];
    const float* W_emb     = (const float*)d_in[3];
    const float* b_emb     = (const float*)d_in[4];
    const float* W_edge    = (const float*)d_in[5];
    const float* b_edge    = (const float*)d_in[6];
    float*       out       = (float*)d_out;

    // workspace layout
    char*   ws    = (char*)d_ws;
    __bf16* Wtb   = (__bf16*)ws;                      // 262,144 B
    float*  w_sym = (float*)(ws + 262144);            //   1,024 B
    float*  g     = (float*)(ws + 262144 + 1024);     // 200,000 B

    prep_kernel<<<229, 256, 0, stream>>>(W_emb, W_edge, Wtb, w_sym, g);

    dim3 ggrid(2, 782);   // x = N-block (cols), y = M-block (rows)
    gemm_g_kernel<<<ggrid, 256, 0, stream>>>(embedding, Wtb, b_emb, w_sym, g);

    edge_kernel<<<NE / 256, 256, 0, stream>>>(g, edges, u, b_edge, out);
}

// Round 4
// 212.842 us; speedup vs baseline: 1.2217x; 1.2217x over previous
//
#include <hip/hip_runtime.h>
#include <hip/hip_bf16.h>

#define NN      50000
#define INDIM   512
#define HIDDEN  256
#define NE      800000
#define BIASF   0.0001f

typedef __attribute__((ext_vector_type(4))) float  f32x4;
typedef __attribute__((ext_vector_type(4))) __bf16 bf16x4;
typedef __attribute__((ext_vector_type(8))) __bf16 bf16x8;

// ---------------------------------------------------------------------------
// prep: blocks 0..31 : Wtb[n][k] = (bf16)W_emb[k][n] via coalesced LDS transpose
//       block  32    : w_sym[j] = 0.5*(We[j]+We[j+256])
// (g is now stored directly by the GEMM -> no zero-init needed)
// ---------------------------------------------------------------------------
__global__ __launch_bounds__(256) void prep_kernel(const float* __restrict__ W_emb,
                                                   const float* __restrict__ W_edge,
                                                   __bf16* __restrict__ Wtb,
                                                   float* __restrict__ w_sym) {
    const int b   = blockIdx.x;
    const int tid = threadIdx.x;
    if (b < 32) {
        // 64(k) x 64(n) f32 tile transpose; 8 k-tiles x 4 n-tiles
        __shared__ float t[64 * 65];
        const int kt = (b >> 2) * 64;
        const int nt = (b & 3) * 64;
        const int rr = tid >> 4;           // 0..15
        const int cc = (tid & 15) * 4;     // 0..60
#pragma unroll
        for (int p = 0; p < 4; ++p) {
            int r = p * 16 + rr;           // k within tile
            f32x4 v = *(const f32x4*)&W_emb[(size_t)(kt + r) * HIDDEN + nt + cc];
            t[(cc + 0) * 65 + r] = v[0];   // store transposed: t[n][k]
            t[(cc + 1) * 65 + r] = v[1];
            t[(cc + 2) * 65 + r] = v[2];
            t[(cc + 3) * 65 + r] = v[3];
        }
        __syncthreads();
#pragma unroll
        for (int p = 0; p < 4; ++p) {
            int n = p * 16 + rr;           // n within tile
            bf16x4 o;
            o[0] = (__bf16)t[n * 65 + cc + 0];
            o[1] = (__bf16)t[n * 65 + cc + 1];
            o[2] = (__bf16)t[n * 65 + cc + 2];
            o[3] = (__bf16)t[n * 65 + cc + 3];
            *(bf16x4*)&Wtb[(size_t)(nt + n) * INDIM + kt + cc] = o;
        }
    } else {
        w_sym[tid] = 0.5f * (W_edge[tid] + W_edge[tid + HIDDEN]);
    }
}

// ---------------------------------------------------------------------------
// Stream-K GEMM + fused node-dot, direct g store (no atomics):
//   g[m] = sum_n relu(emb[m]@W[:,n] + b[n]) * w_sym[n]
// Block = 64 rows x 256 cols (full HIDDEN). 4 waves split N, each 64x64 (4x4
// MFMA tiles). A: each block's 64 rows = one CONTIGUOUS 128 KB global span,
// staged fp32->bf16 into LDS in two K-halves (sequential HBM streaming).
// B: bf16x8 fragments straight from the 256 KB L2-hot Wtb, immediate offsets.
// K-loop per half is barrier-free: ds_read A + global B + MFMA only.
// LDS A stride 264 bf16 (528 B): 4-bank-group rotation -> 2-way aliasing (free).
// ---------------------------------------------------------------------------
__global__ __launch_bounds__(256, 4) void gemm_g_kernel(const float* __restrict__ A,
                                                        const __bf16* __restrict__ Wtb,
                                                        const float* __restrict__ bias,
                                                        const float* __restrict__ w_sym,
                                                        float* __restrict__ g) {
    constexpr int LDA = 264;                 // bf16 elems per LDS row (512/2 + pad 8)
    __shared__ __align__(16) __bf16 As[64 * LDA];
    __shared__ float red[4][64];

    const int tid  = threadIdx.x;
    const int lane = tid & 63;
    const int w    = tid >> 6;               // wave id = N-quarter
    const int ml   = lane & 15, kq = lane >> 4;
    const int m0   = blockIdx.x * 64;

    f32x4 acc[4][4];
#pragma unroll
    for (int i = 0; i < 4; ++i)
#pragma unroll
        for (int j = 0; j < 4; ++j) acc[i][j] = (f32x4)0.0f;

    const __bf16* bp[4];
#pragma unroll
    for (int nt = 0; nt < 4; ++nt) {
        int col = w * 64 + nt * 16 + ml;
        bp[nt] = Wtb + (size_t)col * INDIM + kq * 8;
    }
    const __bf16* afp = As + (size_t)0 + kq * 8;   // + row*LDA added per frag

#pragma unroll
    for (int h = 0; h < 2; ++h) {
        // ---- stage 64 rows x 256 k (64 KB fp32, contiguous per row run) ----
        if (h) __syncthreads();              // waves done reading half 0
#pragma unroll
        for (int j = 0; j < 16; ++j) {
            int i   = j * 256 + tid;         // 0..4095 16B-chunks
            int row = i >> 6;                // 0..63
            int c4  = (i & 63) << 2;         // float idx 0..252
            int gr  = m0 + row; if (gr > NN - 1) gr = NN - 1;
            f32x4 v = *(const f32x4*)(A + (size_t)gr * INDIM + h * 256 + c4);
            bf16x4 o;
            o[0] = (__bf16)v[0]; o[1] = (__bf16)v[1];
            o[2] = (__bf16)v[2]; o[3] = (__bf16)v[3];
            *(bf16x4*)&As[row * LDA + c4] = o;
        }
        __syncthreads();

        // ---- barrier-free K-loop: 8 ksteps of K=32 ----
#pragma unroll
        for (int ks = 0; ks < 8; ++ks) {
            bf16x8 af[4], bf[4];
#pragma unroll
            for (int mt = 0; mt < 4; ++mt)
                af[mt] = *(const bf16x8*)(afp + (mt * 16 + ml) * LDA + ks * 32);
#pragma unroll
            for (int nt = 0; nt < 4; ++nt)
                bf[nt] = *(const bf16x8*)(bp[nt] + h * 256 + ks * 32);
#pragma unroll
            for (int mt = 0; mt < 4; ++mt)
#pragma unroll
                for (int nt = 0; nt < 4; ++nt)
                    acc[mt][nt] = __builtin_amdgcn_mfma_f32_16x16x32_bf16(
                        af[mt], bf[nt], acc[mt][nt], 0, 0, 0);
        }
    }

    // ---- epilogue: relu+dot w_sym, reduce over ml lanes, then over waves ----
    // C/D layout: col = ml, row = kq*4 + reg  [verified m89/m91]
    float wsv[4], bcv[4];
#pragma unroll
    for (int nt = 0; nt < 4; ++nt) {
        int col = w * 64 + nt * 16 + ml;
        wsv[nt] = w_sym[col];
        bcv[nt] = bias[col];
    }
#pragma unroll
    for (int mt = 0; mt < 4; ++mt) {
#pragma unroll
        for (int r = 0; r < 4; ++r) {
            float s = 0.0f;
#pragma unroll
            for (int nt = 0; nt < 4; ++nt) {
                float x = acc[mt][nt][r] + bcv[nt];
                s = fmaf(fmaxf(x, 0.0f), wsv[nt], s);
            }
            s += __shfl_xor(s, 1);
            s += __shfl_xor(s, 2);
            s += __shfl_xor(s, 4);
            s += __shfl_xor(s, 8);
            if (ml == 0) red[w][mt * 16 + kq * 4 + r] = s;
        }
    }
    __syncthreads();
    if (tid < 64) {
        int row = m0 + tid;
        if (row < NN)
            g[row] = red[0][tid] + red[1][tid] + red[2][tid] + red[3][tid];
    }
}

// ---------------------------------------------------------------------------
// edge kernel: one THREAD per edge; g gathers are 4B hits in a 200 KB array.
// ---------------------------------------------------------------------------
__global__ __launch_bounds__(256) void edge_kernel(const float* __restrict__ g,
                                                   const int* __restrict__ edges,
                                                   const float* __restrict__ u,
                                                   const float* __restrict__ b_edge,
                                                   float* __restrict__ out) {
    const int e  = blockIdx.x * 256 + threadIdx.x;      // NE = 3125*256 exactly
    const int i0 = edges[e];
    const int i1 = edges[NE + e];
    float raw = g[i0] + g[i1] + b_edge[0];
    float uu  = u[e];
    float eps = fmaf(uu, BIASF - (1.0f - BIASF), 1.0f - BIASF); // -0.9998u+0.9999
    float gt  = logf(eps) - log1pf(-eps) + raw;                 // TEMPERATURE=1
    out[e] = 1.0f / (1.0f + expf(-gt));
}

// ---------------------------------------------------------------------------
extern "C" void kernel_launch(void* const* d_in, const int* in_sizes, int n_in,
                              void* d_out, int out_size, void* d_ws, size_t ws_size,
                              hipStream_t stream) {
    const float* embedding = (const float*)d_in[0];
    const int*   edges     = (const int*)d_in[1];
    const float* u         = (const float*)d_in[2];
    const float* W_emb     = (const float*)d_in[3];
    const float* b_emb     = (const float*)d_in[4];
    const float* W_edge    = (const float*)d_in[5];
    const float* b_edge    = (const float*)d_in[6];
    float*       out       = (float*)d_out;

    // workspace layout
    char*   ws    = (char*)d_ws;
    __bf16* Wtb   = (__bf16*)ws;                      // 262,144 B
    float*  w_sym = (float*)(ws + 262144);            //   1,024 B
    float*  g     = (float*)(ws + 262144 + 1024);     // 200,000 B

    prep_kernel<<<33, 256, 0, stream>>>(W_emb, W_edge, Wtb, w_sym);

    gemm_g_kernel<<<782, 256, 0, stream>>>(embedding, Wtb, b_emb, w_sym, g);

    edge_kernel<<<NE / 256, 256, 0, stream>>>(g, edges, u, b_edge, out);
}

// Round 5
// 200.953 us; speedup vs baseline: 1.2939x; 1.0592x over previous
//
#include <hip/hip_runtime.h>
#include <hip/hip_bf16.h>

#define NN      50000
#define INDIM   512
#define HIDDEN  256
#define NE      800000
#define BIASF   0.0001f

typedef __attribute__((ext_vector_type(4))) float  f32x4;
typedef __attribute__((ext_vector_type(4))) __bf16 bf16x4;
typedef __attribute__((ext_vector_type(8))) __bf16 bf16x8;

// async global->LDS DMA, 16 B per lane, no VGPR round-trip [m97]
__device__ __forceinline__ void async_copy16(const float* gp, float* lp) {
    __builtin_amdgcn_global_load_lds(
        (const __attribute__((address_space(1))) void*)gp,
        (__attribute__((address_space(3))) void*)lp,
        16, 0, 0);
}

// ---------------------------------------------------------------------------
// prep: blocks 0..31 : Wtb[n][k] = (bf16)W_emb[k][n] via coalesced LDS transpose
//       block  32    : w_sym[j] = 0.5*(We[j]+We[j+256])
// ---------------------------------------------------------------------------
__global__ __launch_bounds__(256) void prep_kernel(const float* __restrict__ W_emb,
                                                   const float* __restrict__ W_edge,
                                                   __bf16* __restrict__ Wtb,
                                                   float* __restrict__ w_sym) {
    const int b   = blockIdx.x;
    const int tid = threadIdx.x;
    if (b < 32) {
        __shared__ float t[64 * 65];
        const int kt = (b >> 2) * 64;
        const int nt = (b & 3) * 64;
        const int rr = tid >> 4;           // 0..15
        const int cc = (tid & 15) * 4;     // 0..60
#pragma unroll
        for (int p = 0; p < 4; ++p) {
            int r = p * 16 + rr;
            f32x4 v = *(const f32x4*)&W_emb[(size_t)(kt + r) * HIDDEN + nt + cc];
            t[(cc + 0) * 65 + r] = v[0];
            t[(cc + 1) * 65 + r] = v[1];
            t[(cc + 2) * 65 + r] = v[2];
            t[(cc + 3) * 65 + r] = v[3];
        }
        __syncthreads();
#pragma unroll
        for (int p = 0; p < 4; ++p) {
            int n = p * 16 + rr;
            bf16x4 o;
            o[0] = (__bf16)t[n * 65 + cc + 0];
            o[1] = (__bf16)t[n * 65 + cc + 1];
            o[2] = (__bf16)t[n * 65 + cc + 2];
            o[3] = (__bf16)t[n * 65 + cc + 3];
            *(bf16x4*)&Wtb[(size_t)(nt + n) * INDIM + kt + cc] = o;
        }
    } else {
        w_sym[tid] = 0.5f * (W_edge[tid] + W_edge[tid + HIDDEN]);
    }
}

// ---------------------------------------------------------------------------
// Stream-K GEMM + fused node-dot, async-DMA staging:
//   g[m] = sum_n relu(emb[m]@W[:,n] + b[n]) * w_sym[n]
// BM=64 rows x full HIDDEN cols; 4 waves split N, each 64x64 (4x4 MFMA tiles).
// A staged fp32 via global_load_lds width=16 (16 KB in flight per wave),
// K in two halves, single LDS buffer. Row stride 260 f32 (1040 B): fragment
// ds_read_b128 lands 2-way bank-aliased = free [m136]. fp32->bf16 cvt at
// fragment read, hidden under MFMA. B: bf16x8 direct from 256 KB L2-hot Wtb.
// ---------------------------------------------------------------------------
__global__ __launch_bounds__(256, 2) void gemm_g_kernel(const float* __restrict__ A,
                                                        const __bf16* __restrict__ Wtb,
                                                        const float* __restrict__ bias,
                                                        const float* __restrict__ w_sym,
                                                        float* __restrict__ g) {
    constexpr int LDA = 260;                     // f32 per LDS row (256 + 4 pad)
    __shared__ __align__(16) float As[64 * LDA]; // 66,560 B -> 2 blocks/CU
    __shared__ float red[4][64];

    const int tid  = threadIdx.x;
    const int lane = tid & 63;
    const int w    = tid >> 6;                   // wave id = N-quarter
    const int ml   = lane & 15, kq = lane >> 4;
    const int m0   = blockIdx.x * 64;

    f32x4 acc[4][4];
#pragma unroll
    for (int i = 0; i < 4; ++i)
#pragma unroll
        for (int j = 0; j < 4; ++j) acc[i][j] = (f32x4)0.0f;

    const __bf16* bp[4];
#pragma unroll
    for (int nt = 0; nt < 4; ++nt) {
        int col = w * 64 + nt * 16 + ml;
        bp[nt] = Wtb + (size_t)col * INDIM + kq * 8;
    }

#pragma unroll
    for (int h = 0; h < 2; ++h) {
        if (h) __syncthreads();                  // all waves done reading half 0
        // ---- async stage: 16 rows per wave, 1 KB contiguous per instruction ----
#pragma unroll
        for (int j = 0; j < 16; ++j) {
            int r  = w * 16 + j;
            int gr = m0 + r; if (gr > NN - 1) gr = NN - 1;   // M-tail clamp
            const float* gp = A + (size_t)gr * INDIM + h * 256 + lane * 4;
            async_copy16(gp, &As[r * LDA]);
        }
        __syncthreads();                         // drains vmcnt -> DMA complete

        // ---- barrier-free K-loop: 8 ksteps of K=32 ----
#pragma unroll
        for (int ks = 0; ks < 8; ++ks) {
            bf16x8 af[4], bfr[4];
#pragma unroll
            for (int mt = 0; mt < 4; ++mt) {
                const float* lf = &As[(mt * 16 + ml) * LDA + ks * 32 + kq * 8];
                f32x4 lo = *(const f32x4*)lf;
                f32x4 hi = *(const f32x4*)(lf + 4);
                af[mt][0] = (__bf16)lo[0]; af[mt][1] = (__bf16)lo[1];
                af[mt][2] = (__bf16)lo[2]; af[mt][3] = (__bf16)lo[3];
                af[mt][4] = (__bf16)hi[0]; af[mt][5] = (__bf16)hi[1];
                af[mt][6] = (__bf16)hi[2]; af[mt][7] = (__bf16)hi[3];
            }
#pragma unroll
            for (int nt = 0; nt < 4; ++nt)
                bfr[nt] = *(const bf16x8*)(bp[nt] + h * 256 + ks * 32);
#pragma unroll
            for (int mt = 0; mt < 4; ++mt)
#pragma unroll
                for (int nt = 0; nt < 4; ++nt)
                    acc[mt][nt] = __builtin_amdgcn_mfma_f32_16x16x32_bf16(
                        af[mt], bfr[nt], acc[mt][nt], 0, 0, 0);
        }
    }

    // ---- epilogue: relu+dot w_sym, xor-reduce over ml lanes, cross-wave LDS ----
    // C/D layout: col = ml, row = kq*4 + reg  [verified m89/m91]
    float wsv[4], bcv[4];
#pragma unroll
    for (int nt = 0; nt < 4; ++nt) {
        int col = w * 64 + nt * 16 + ml;
        wsv[nt] = w_sym[col];
        bcv[nt] = bias[col];
    }
#pragma unroll
    for (int mt = 0; mt < 4; ++mt) {
#pragma unroll
        for (int r = 0; r < 4; ++r) {
            float s = 0.0f;
#pragma unroll
            for (int nt = 0; nt < 4; ++nt) {
                float x = acc[mt][nt][r] + bcv[nt];
                s = fmaf(fmaxf(x, 0.0f), wsv[nt], s);
            }
            s += __shfl_xor(s, 1);
            s += __shfl_xor(s, 2);
            s += __shfl_xor(s, 4);
            s += __shfl_xor(s, 8);
            if (ml == 0) red[w][mt * 16 + kq * 4 + r] = s;
        }
    }
    __syncthreads();
    if (tid < 64) {
        int row = m0 + tid;
        if (row < NN)
            g[row] = red[0][tid] + red[1][tid] + red[2][tid] + red[3][tid];
    }
}

// ---------------------------------------------------------------------------
// edge kernel: one THREAD per edge; g gathers are 4B hits in a 200 KB array.
// ---------------------------------------------------------------------------
__global__ __launch_bounds__(256) void edge_kernel(const float* __restrict__ g,
                                                   const int* __restrict__ edges,
                                                   const float* __restrict__ u,
                                                   const float* __restrict__ b_edge,
                                                   float* __restrict__ out) {
    const int e  = blockIdx.x * 256 + threadIdx.x;      // NE = 3125*256 exactly
    const int i0 = edges[e];
    const int i1 = edges[NE + e];
    float raw = g[i0] + g[i1] + b_edge[0];
    float uu  = u[e];
    float eps = fmaf(uu, BIASF - (1.0f - BIASF), 1.0f - BIASF); // -0.9998u+0.9999
    float gt  = logf(eps) - log1pf(-eps) + raw;                 // TEMPERATURE=1
    out[e] = 1.0f / (1.0f + expf(-gt));
}

// ---------------------------------------------------------------------------
extern "C" void kernel_launch(void* const* d_in, const int* in_sizes, int n_in,
                              void* d_out, int out_size, void* d_ws, size_t ws_size,
                              hipStream_t stream) {
    const float* embedding = (const float*)d_in[0];
    const int*   edges     = (const int*)d_in[1];
    const float* u         = (const float*)d_in[2];
    const float* W_emb     = (const float*)d_in[3];
    const float* b_emb     = (const float*)d_in[4];
    const float* W_edge    = (const float*)d_in[5];
    const float* b_edge    = (const float*)d_in[6];
    float*       out       = (float*)d_out;

    // workspace layout
    char*   ws    = (char*)d_ws;
    __bf16* Wtb   = (__bf16*)ws;                      // 262,144 B
    float*  w_sym = (float*)(ws + 262144);            //   1,024 B
    float*  g     = (float*)(ws + 262144 + 1024);     // 200,000 B

    prep_kernel<<<33, 256, 0, stream>>>(W_emb, W_edge, Wtb, w_sym);

    gemm_g_kernel<<<782, 256, 0, stream>>>(embedding, Wtb, b_emb, w_sym, g);

    edge_kernel<<<NE / 256, 256, 0, stream>>>(g, edges, u, b_edge, out);
}